// Round 12
// baseline (29.011 us; speedup 1.0000x reference)
//
#include <hip/hip_runtime.h>

typedef _Float16 f16;
typedef __attribute__((ext_vector_type(2))) _Float16 f16x2;
typedef __attribute__((ext_vector_type(4))) _Float16 f16x4;
typedef __attribute__((ext_vector_type(8))) _Float16 f16x8;
typedef __attribute__((ext_vector_type(4))) float f32x4;
typedef __attribute__((ext_vector_type(4))) unsigned u32x4;

constexpr int IN_F  = 4096;
constexpr int OUT_F = 11008;
constexpr int NGRP  = 32;            // 4096 / 128
constexpr int NTILE = OUT_F / 16;    // 688
constexpr int PLANE = OUT_F * 8;     // floats per split-K partial plane

// dequant one byte-holding int32 (2 nibbles) -> 2 packed f16 weights
__device__ __forceinline__ unsigned dq2(unsigned q, f16x2 sp, f16x2 zp) {
    unsigned t = (((q << 12) | q) & 0x000F000Fu) | 0x64006400u;  // (1024+lo, 1024+hi)
    f16x2 u = __builtin_bit_cast(f16x2, t);
    u = u - (f16x2){(_Float16)1024.0f, (_Float16)1024.0f};       // exact
    u = u * sp + zp;                                             // v_pk_fma_f16
    return __builtin_bit_cast(unsigned, u);
}

__device__ __forceinline__ f16x2 bcast(float v) {
    _Float16 h = (_Float16)v;
    return (f16x2){h, h};
}

// x f32 [8][4096] -> f16 [16][4096] workspace; rows 8..15 zeroed so the main
// kernel's A-fragment loads are branch-free (exact vmcnt accounting).
__global__ void xprep16_kernel(const float* __restrict__ x, f16* __restrict__ xh) {
    const int i4  = blockIdx.x * blockDim.x + threadIdx.x;   // 16*4096/4 = 16384
    const int k4  = i4 * 4;
    const int row = k4 >> 12;           // /4096
    const int kk  = k4 & 4095;
    f16x4 r;
    if (row < 8) {
        float4 v = *(const float4*)(x + (size_t)row * IN_F + kk);
        r = (f16x4){(f16)v.x, (f16)v.y, (f16)v.z, (f16)v.w};
    } else {
        r = (f16x4){0, 0, 0, 0};
    }
    *(f16x4*)(xh + (size_t)row * IN_F + kk) = r;
}

// 2752 blocks (688 o-tiles x 4 split-K) x 4 waves. Wave = private 256-k slab.
// ALL 18 vmem ops issued up-front in pinned FIFO order:
//   [sg zg] [W0 W1 x0 x1] [W2 W3 x2 x3] [W4 W5 x4 x5] [W6 W7 x6 x7]
// (~10 KB in flight per wave), then compute sub-slab ss after vmcnt(12-4ss):
// compute starts at FIRST arrival. No re-staging -> no WAR hazards, counts
// monotone. Both-sides XOR swizzle ^((row&7)<<4) on gload_lds src + LDS read.
__global__ __launch_bounds__(256, 4)
void qlin_burst(const int* __restrict__ wq,
                const float* __restrict__ scales,
                const float* __restrict__ zeros,
                const f16* __restrict__ xh,
                float* __restrict__ wsf)
{
    __shared__ unsigned char wlds[4][8192];   // 32 KB: 8 KB per wave

    const int tid  = threadIdx.x;
    const int wv   = tid >> 6;
    const int lane = tid & 63;
    const int col  = lane & 15;      // weight row in tile / MFMA n; A row m
    const int kg   = lane >> 4;
    const int bid  = blockIdx.x;
    const int kq   = bid & 3;        // split-K quarter
    const int ot   = bid >> 2;       // o-tile
    const int o0   = ot * 16;
    const int orow = o0 + col;
    const int k0   = kq * 1024 + wv * 256;   // wave's 256-k slab (2 groups)
    const int g0   = k0 >> 7;

    // vmem ops 1,2 (oldest in FIFO)
    float2 sg = *(const float2*)(scales + (size_t)orow * NGRP + g0);
    float2 zg = *(const float2*)(zeros  + (size_t)orow * NGRP + g0);
    __builtin_amdgcn_sched_barrier(0);

    const char* wb   = (const char*)wq;
    const int   coff = (lane & 7) * 16;
    const f16*  xcol = xh + (size_t)col * IN_F + k0 + kg * 8;  // rows 8..15 = 0

    f16x8 af[4][2];

    // burst: per sub-slab ss: 2 gload_lds (16 rows x 128B, swizzled src) + 2 x
    #pragma unroll
    for (int ss = 0; ss < 4; ++ss) {
        #pragma unroll
        for (int j = 0; j < 2; ++j) {
            const int r = j * 8 + (lane >> 3);
            const char* src = wb + (size_t)(o0 + r) * 8192
                              + (size_t)(k0 + ss * 64) * 2
                              + (coff ^ ((r & 7) << 4));
            __builtin_amdgcn_global_load_lds(
                (const __attribute__((address_space(1))) void*)src,
                (__attribute__((address_space(3))) void*)&wlds[wv][ss * 2048 + j * 1024],
                16, 0, 0);
        }
        af[ss][0] = *(const f16x8*)(xcol + ss * 64);
        af[ss][1] = *(const f16x8*)(xcol + ss * 64 + 32);
        __builtin_amdgcn_sched_barrier(0);
    }

    // LDS read base for this lane: row=col chunk within sub-slab
    const unsigned rswz  = (unsigned)((col & 7) << 4);
    const unsigned rbase = (unsigned)((col >> 3) * 1024 + (col & 7) * 128);

    f32x4 acc = {0.f, 0.f, 0.f, 0.f};

    #pragma unroll
    for (int ss = 0; ss < 4; ++ss) {
        // first 2 + 4*(ss+1) ops done -> sub-slab ss's W+x (and s/z) landed
        if      (ss == 0) asm volatile("s_waitcnt vmcnt(12)" ::: "memory");
        else if (ss == 1) asm volatile("s_waitcnt vmcnt(8)"  ::: "memory");
        else if (ss == 2) asm volatile("s_waitcnt vmcnt(4)"  ::: "memory");
        else              asm volatile("s_waitcnt vmcnt(0)"  ::: "memory");
        __builtin_amdgcn_sched_barrier(0);

        const unsigned char* buf = &wlds[wv][ss * 2048];
        const int4 qa = *(const int4*)(buf + rbase + ((     kg * 16) ^ rswz));
        const int4 qb = *(const int4*)(buf + rbase + ((64 + kg * 16) ^ rswz));

        const f16x2 s2 = bcast((ss < 2) ? sg.x : sg.y);
        const f16x2 z2 = bcast((ss < 2) ? zg.x : zg.y);
        u32x4 ba = {dq2((unsigned)qa.x, s2, z2), dq2((unsigned)qa.y, s2, z2),
                    dq2((unsigned)qa.z, s2, z2), dq2((unsigned)qa.w, s2, z2)};
        u32x4 bb = {dq2((unsigned)qb.x, s2, z2), dq2((unsigned)qb.y, s2, z2),
                    dq2((unsigned)qb.z, s2, z2), dq2((unsigned)qb.w, s2, z2)};
        acc = __builtin_amdgcn_mfma_f32_16x16x32_f16(af[ss][0],
                __builtin_bit_cast(f16x8, ba), acc, 0, 0, 0);
        acc = __builtin_amdgcn_mfma_f32_16x16x32_f16(af[ss][1],
                __builtin_bit_cast(f16x8, bb), acc, 0, 0, 0);
    }

    // cross-wave reduce (LDS reuse: each wave writes only its own 8KB chunk)
    *(f32x4*)&wlds[wv][lane * 16] = acc;
    __syncthreads();

    if (tid < 32) {   // rows 0..7: mbase = (tid>>4)*4 in {0,4}
        f32x4 ssum = *(const f32x4*)&wlds[0][tid * 16];
        #pragma unroll
        for (int w = 1; w < 4; ++w)
            ssum += *(const f32x4*)&wlds[w][tid * 16];
        const int n = tid & 15;
        const int mbase = (tid >> 4) * 4;
        float* plane = wsf + (size_t)kq * PLANE;
        #pragma unroll
        for (int i = 0; i < 4; ++i)
            plane[(size_t)(mbase + i) * OUT_F + o0 + n] = ssum[i];
    }
}

// out[idx] = bias[o] + sum of 4 split-K planes
__global__ __launch_bounds__(256)
void reduce_kernel(const float* __restrict__ wsf,
                   const float* __restrict__ bias,
                   float* __restrict__ out)
{
    const int idx = blockIdx.x * 256 + threadIdx.x;   // 0..88063
    const int o = idx % OUT_F;
    out[idx] = bias[o] + wsf[idx] + wsf[PLANE + idx]
             + wsf[2 * PLANE + idx] + wsf[3 * PLANE + idx];
}

// ---------------- fallback (R5-style, used only if ws too small) ------------
__global__ __launch_bounds__(256, 4)
void qlin_kernel(const int* __restrict__ wq,
                 const float* __restrict__ scales,
                 const float* __restrict__ zeros,
                 const float* __restrict__ bias,
                 const float* __restrict__ xf,
                 float* __restrict__ out)
{
    __shared__ unsigned char wlds[2][16][1024];
    __shared__ f32x4 red[4][64];

    const int tid  = threadIdx.x;
    const int wv   = tid >> 6;
    const int lane = tid & 63;
    const int col  = lane & 15;
    const int kg   = lane >> 4;
    const int o0   = blockIdx.x * 16;
    const int orow = o0 + col;
    const bool mvalid = (col < 8);

    f16x2 sp[8], zp[8];
    #pragma unroll
    for (int s = 0; s < 8; ++s) {
        sp[s] = bcast(scales[(size_t)orow * NGRP + s * 4 + wv]);
        zp[s] = bcast(zeros [(size_t)orow * NGRP + s * 4 + wv]);
    }

    const char* wtile = (const char*)wq + (size_t)o0 * 8192;
    auto stage = [&](int sl, int bufi) {
        #pragma unroll
        for (int c = 0; c < 4; ++c) {
            const int r = 4 * wv + c;
            const char* src = wtile + (size_t)r * 8192 + sl * 1024
                              + ((lane * 16) ^ ((r & 7) << 4));
            __builtin_amdgcn_global_load_lds(
                (const __attribute__((address_space(1))) void*)src,
                (__attribute__((address_space(3))) void*)&wlds[bufi][r][0],
                16, 0, 0);
        }
    };

    stage(0, 0);
    stage(1, 1);

    const float* xfcol = xf + (size_t)col * IN_F;
    const unsigned swz = (unsigned)((col & 7) << 4);
    f32x4 acc = {0.f, 0.f, 0.f, 0.f};

    #pragma unroll
    for (int s = 0; s < 8; ++s) {
        asm volatile("s_waitcnt vmcnt(0)" ::: "memory");
        __builtin_amdgcn_s_barrier();
        asm volatile("" ::: "memory");

        const f16x2 s2 = sp[s], z2 = zp[s];
        #pragma unroll
        for (int t = 0; t < 4; ++t) {
            const int k = s * 512 + wv * 128 + t * 32 + kg * 8;
            f16x8 af = (f16x8){0,0,0,0,0,0,0,0};
            if (mvalid) {
                float4 a0 = *(const float4*)(xfcol + k);
                float4 a1 = *(const float4*)(xfcol + k + 4);
                af = (f16x8){(f16)a0.x,(f16)a0.y,(f16)a0.z,(f16)a0.w,
                             (f16)a1.x,(f16)a1.y,(f16)a1.z,(f16)a1.w};
            }
            const unsigned off = ((unsigned)(wv * 256 + t * 64 + kg * 16)) ^ swz;
            const int4 q = *(const int4*)&wlds[s & 1][col][off];
            u32x4 bw = {dq2((unsigned)q.x, s2, z2),
                        dq2((unsigned)q.y, s2, z2),
                        dq2((unsigned)q.z, s2, z2),
                        dq2((unsigned)q.w, s2, z2)};
            f16x8 bfr = __builtin_bit_cast(f16x8, bw);
            acc = __builtin_amdgcn_mfma_f32_16x16x32_f16(af, bfr, acc, 0, 0, 0);
        }

        asm volatile("" ::: "memory");
        __builtin_amdgcn_s_barrier();
        if (s < 6) stage(s + 2, s & 1);
    }

    red[wv][lane] = acc;
    __syncthreads();

    if (tid < 64) {
        f32x4 ssum = red[0][tid];
        #pragma unroll
        for (int w = 1; w < 4; ++w) ssum += red[w][tid];
        const int n = tid & 15;
        const float bb = bias[o0 + n];
        const int mbase = (tid >> 4) * 4;
        if (mbase < 8) {
            #pragma unroll
            for (int i = 0; i < 4; ++i)
                out[(size_t)(mbase + i) * OUT_F + o0 + n] = ssum[i] + bb;
        }
    }
}

extern "C" void kernel_launch(void* const* d_in, const int* in_sizes, int n_in,
                              void* d_out, int out_size, void* d_ws, size_t ws_size,
                              hipStream_t stream) {
    const float* x  = (const float*)d_in[0];
    const int*   wq = (const int*)d_in[1];
    const float* sc = (const float*)d_in[2];
    const float* zr = (const float*)d_in[3];
    const float* bs = (const float*)d_in[4];
    float* out = (float*)d_out;
    (void)in_sizes; (void)n_in;

    const size_t planes_b = (size_t)4 * PLANE * sizeof(float);
    const size_t xh_b     = (size_t)16 * IN_F * sizeof(f16);   // 16 rows (padded)

    if (ws_size >= planes_b + xh_b) {
        float* wsf = (float*)d_ws;
        f16*   xh  = (f16*)((char*)d_ws + planes_b);
        xprep16_kernel<<<(16 * IN_F) / (256 * 4), 256, 0, stream>>>(x, xh);
        qlin_burst<<<NTILE * 4, 256, 0, stream>>>(wq, sc, zr, xh, wsf);
        reduce_kernel<<<PLANE / 256, 256, 0, stream>>>(wsf, bs, out);
    } else {
        qlin_kernel<<<NTILE, 256, 0, stream>>>(wq, sc, zr, bs, x, out);
    }
}